// Round 3
// baseline (1421.267 us; speedup 1.0000x reference)
//
#include <hip/hip_runtime.h>

// Problem: B=4, S=8192, D=1024, E=64, K=2; tokens=32768; capacity=640
// Outputs (flat f32, concat): idx[65536] | norm_probs[65536] | gate_probs[2097152]
//                             | loss[1] | capacity_mask[65536]
#define CAPACITY 640

// ------- prep: transpose W[64][1024] -> Wt[1024][64] (f32, exact), zero psum
__global__ void prep_kernel(const float* __restrict__ Wg,
                            float* __restrict__ Wt,
                            float* __restrict__ psum) {
    const int g = (int)(blockIdx.x * 256 + threadIdx.x);     // 65536 threads
    const int e = g >> 10;
    const int k = g & 1023;
    Wt[(k << 6) + e] = Wg[g];
    if (g < 64) psum[g] = 0.0f;
}

// ---------------- main gate kernel --------------------------------------
// grid 512 (64 tokens each), block 256 = 4 waves; wave w owns experts [16w,16w+16)
// Logits emulate numpy's einsum fp32 SSE3 dot product BIT-EXACTLY:
//   - 4 lane-partials (lane j sums d with d&3==j), no FMA (contract off)
//   - per 16-elem block, adds in group order 3,2,1,0 (chained muladd emulation)
//   - final combine (p0+p1)+(p2+p3)  (SSE3 hadd tree)
__global__ __launch_bounds__(256) void gate_kernel(
    const float* __restrict__ hs, const float* __restrict__ Wt,
    float* __restrict__ out_idx, float* __restrict__ gp,
    float* __restrict__ psum, float4* __restrict__ rec, int* __restrict__ hist)
{
#pragma clang fp contract(off)
    __shared__ float  lds_h[2][2048];   // [buf][64 rows * 32 floats], source-swizzled
    __shared__ float  red_m[4][64];
    __shared__ float  red_s[4][64];
    __shared__ float2 red_v[4][64];     // slice top-2 values
    __shared__ int2   red_i[4][64];     // slice top-2 indices

    const int tid  = (int)threadIdx.x;
    const int lane = tid & 63;
    const int w    = tid >> 6;
    const int woff = __builtin_amdgcn_readfirstlane(w << 4);  // SGPR -> s_load for W
    const int tokBase = (int)blockIdx.x << 6;

    float acc[16][4];                   // [expert][sse lane j]
#pragma unroll
    for (int e = 0; e < 16; ++e)
#pragma unroll
        for (int j = 0; j < 4; ++j) acc[e][j] = 0.0f;

    const int r8  = lane >> 3;            // row-within-8 for staging
    const int kgl = (lane & 7) ^ r8;      // pre-swizzled 16B-group (bank-conflict fix)

    auto stage = [&](int buf, int c) {
#pragma unroll
        for (int ii = 0; ii < 2; ++ii) {
            const int i = (w << 1) + ii;  // wave-uniform call index 0..7
            const float* g = hs + (size_t)(tokBase + (i << 3) + r8) * 1024
                                + (c << 5) + (kgl << 2);
            __builtin_amdgcn_global_load_lds(
                (__attribute__((address_space(1))) void*)g,
                (__attribute__((address_space(3))) void*)&lds_h[buf][i << 8],
                16, 0, 0);
        }
    };

    stage(0, 0);
    __syncthreads();
    int buf = 0;
    for (int c = 0; c < 32; ++c) {
        if (c < 31) stage(buf ^ 1, c + 1);            // prefetch next chunk
        const float* wbase = Wt + (((size_t)(c << 5)) << 6) + woff;
#pragma unroll
        for (int gi = 0; gi < 8; ++gi) {
            constexpr int gordv[8] = {3, 2, 1, 0, 7, 6, 5, 4};  // np chain order
            const int g = gordv[gi];
            const float4 h4 = *(const float4*)
                &lds_h[buf][(lane << 5) + ((g ^ (lane & 7)) << 2)];
            const float hv[4] = {h4.x, h4.y, h4.z, h4.w};
#pragma unroll
            for (int j = 0; j < 4; ++j) {
                const float* row = wbase + (((g << 2) + j) << 6);  // uniform -> s_load
                const float h = hv[j];
#pragma unroll
                for (int e = 0; e < 16; ++e) {
                    const float t = h * row[e];       // separate round (no FMA)
                    acc[e][j] = acc[e][j] + t;        // separate round
                }
            }
        }
        __syncthreads();   // drains vmcnt for the prefetch, flips epoch
        buf ^= 1;
    }

    // final horizontal combine, numpy npyv_sum_f32 (SSE3): (p0+p1)+(p2+p3)
    float logit[16];
#pragma unroll
    for (int e = 0; e < 16; ++e) {
        const float s01 = acc[e][0] + acc[e][1];
        const float s23 = acc[e][2] + acc[e][3];
        logit[e] = s01 + s23;
    }

    // ---- epilogue: cross-wave softmax assembly (lane = token) ----
    float m = logit[0];
#pragma unroll
    for (int e = 1; e < 16; ++e) m = fmaxf(m, logit[e]);
    red_m[w][lane] = m;
    __syncthreads();
    const float gm = fmaxf(fmaxf(red_m[0][lane], red_m[1][lane]),
                           fmaxf(red_m[2][lane], red_m[3][lane]));
    float p[16];
    float s = 0.0f;
#pragma unroll
    for (int e = 0; e < 16; ++e) { p[e] = __expf(logit[e] - gm); s += p[e]; }
    red_s[w][lane] = s;

    // slice top-2 on f32 logits (strict > keeps lowest index on ties)
    float v1 = -3.4e38f, v2 = -3.4e38f; int i1 = 0, i2 = 0;
#pragma unroll
    for (int e = 0; e < 16; ++e) {
        const float v = logit[e];
        if (v > v1)      { v2 = v1; i2 = i1; v1 = v; i1 = woff + e; }
        else if (v > v2) { v2 = v;  i2 = woff + e; }
    }
    red_v[w][lane] = make_float2(v1, v2);
    red_i[w][lane] = make_int2(i1, i2);
    __syncthreads();
    const float stot = red_s[0][lane] + red_s[1][lane] + red_s[2][lane] + red_s[3][lane];
    const float inv  = 1.0f / stot;
    const int token  = tokBase + lane;

    // gate_probs slice store + per-expert prob sums
    float pn[16];
#pragma unroll
    for (int e = 0; e < 16; ++e) pn[e] = p[e] * inv;
#pragma unroll
    for (int jj = 0; jj < 4; ++jj) {
        *(float4*)&gp[(size_t)token * 64 + woff + 4 * jj] =
            make_float4(pn[4*jj], pn[4*jj+1], pn[4*jj+2], pn[4*jj+3]);
    }
    float mysum = 0.0f;
#pragma unroll
    for (int e = 0; e < 16; ++e) {
        float v = pn[e];
        v += __shfl_xor(v, 1, 64);  v += __shfl_xor(v, 2, 64);
        v += __shfl_xor(v, 4, 64);  v += __shfl_xor(v, 8, 64);
        v += __shfl_xor(v, 16, 64); v += __shfl_xor(v, 32, 64);
        if (lane == e) mysum = v;
    }
    if (lane < 16) atomicAdd(&psum[woff + lane], mysum);

    if (w == 0) {
        // merge 4 slice top-2s (ascending index blocks -> ties keep earlier)
        float g1 = red_v[0][lane].x, g2 = red_v[0][lane].y;
        int gi1 = red_i[0][lane].x,  gi2 = red_i[0][lane].y;
#pragma unroll
        for (int ww = 1; ww < 4; ++ww) {
            const float b1 = red_v[ww][lane].x, b2 = red_v[ww][lane].y;
            const int bi1 = red_i[ww][lane].x,  bi2 = red_i[ww][lane].y;
            if (b1 > g1)      { g2 = g1; gi2 = gi1; g1 = b1; gi1 = bi1; }
            else if (b1 > g2) { g2 = b1; gi2 = bi1; }
            if (b2 > g2)      { g2 = b2; gi2 = bi2; }
        }
        const float p1 = __expf(g1 - gm) * inv;
        const float p2 = __expf(g2 - gm) * inv;
        *(float2*)&out_idx[2 * token] = make_float2((float)gi1, (float)gi2);
        rec[token] = make_float4(__int_as_float(gi1 | (gi2 << 8)), p1, p2, 0.0f);

        // per-block expert histogram via 6-bit ballot match (no LDS atomics)
        int cnt = 0;
#pragma unroll
        for (int which = 0; which < 2; ++which) {
            const int ei = which ? gi2 : gi1;
            const unsigned long long m0 = __ballot(ei & 1);
            const unsigned long long m1 = __ballot((ei >> 1) & 1);
            const unsigned long long m2 = __ballot((ei >> 2) & 1);
            const unsigned long long m3 = __ballot((ei >> 3) & 1);
            const unsigned long long m4 = __ballot((ei >> 4) & 1);
            const unsigned long long m5 = __ballot((ei >> 5) & 1);
            unsigned long long mine = (lane & 1)        ? m0 : ~m0;
            mine &= ((lane >> 1) & 1) ? m1 : ~m1;
            mine &= ((lane >> 2) & 1) ? m2 : ~m2;
            mine &= ((lane >> 3) & 1) ? m3 : ~m3;
            mine &= ((lane >> 4) & 1) ? m4 : ~m4;
            mine &= ((lane >> 5) & 1) ? m5 : ~m5;
            cnt += __popcll(mine);   // # lanes whose index == my lane id
        }
        hist[((int)blockIdx.x << 6) + lane] = cnt;
    }
}

// ---------------- scan: capacity ranks + outputs + loss ------------------
// blocks 0..127: 512 slots each; block 128: loss. 64 threads = 1 wave.
__global__ __launch_bounds__(64) void scan_kernel(
    const int* __restrict__ hist, const float4* __restrict__ rec,
    const float* __restrict__ psum, float* __restrict__ out_np,
    float* __restrict__ out_cm, float* __restrict__ out_loss)
{
    const int lane = (int)threadIdx.x;
    const int b = (int)blockIdx.x;
    if (b < 128) {
        int cnt = 0;                       // lane l = running count for expert l
        const int abase = b << 2;          // 4 gate-blocks per scan-block
        for (int a = 0; a < abase; ++a) cnt += hist[(a << 6) + lane];
#pragma unroll
        for (int it = 0; it < 8; ++it) {
            const int slot  = (b << 9) + (it << 6) + lane;
            const int token = slot >> 1;
            const int kk    = slot & 1;
            const float4 r  = rec[token];
            const int packed = __float_as_int(r.x);
            const int e  = kk ? ((packed >> 8) & 63) : (packed & 63);
            const float pv = kk ? r.z : r.y;
            const unsigned long long m0 = __ballot(e & 1);
            const unsigned long long m1 = __ballot((e >> 1) & 1);
            const unsigned long long m2 = __ballot((e >> 2) & 1);
            const unsigned long long m3 = __ballot((e >> 3) & 1);
            const unsigned long long m4 = __ballot((e >> 4) & 1);
            const unsigned long long m5 = __ballot((e >> 5) & 1);
            unsigned long long peers = (e & 1)        ? m0 : ~m0;
            peers &= ((e >> 1) & 1) ? m1 : ~m1;
            peers &= ((e >> 2) & 1) ? m2 : ~m2;
            peers &= ((e >> 3) & 1) ? m3 : ~m3;
            peers &= ((e >> 4) & 1) ? m4 : ~m4;
            peers &= ((e >> 5) & 1) ? m5 : ~m5;
            unsigned long long mine = (lane & 1)        ? m0 : ~m0;
            mine &= ((lane >> 1) & 1) ? m1 : ~m1;
            mine &= ((lane >> 2) & 1) ? m2 : ~m2;
            mine &= ((lane >> 3) & 1) ? m3 : ~m3;
            mine &= ((lane >> 4) & 1) ? m4 : ~m4;
            mine &= ((lane >> 5) & 1) ? m5 : ~m5;
            const int base = __shfl(cnt, e, 64);
            const int rank = base + __popcll(peers & ((1ull << lane) - 1ull));
            const bool keep = rank < CAPACITY;
            cnt += __popcll(mine);
            const float masked = keep ? pv : 0.0f;
            const float other  = __shfl_xor(masked, 1, 64);
            float denom = masked + other;
            denom = denom > 1e-8f ? denom : 1e-8f;
            out_np[slot] = masked / denom;
            out_cm[slot] = keep ? 1.0f : 0.0f;
        }
    } else {
        int tot = 0;
        for (int a = 0; a < 512; ++a) tot += hist[(a << 6) + lane];
        float v = (psum[lane] * (1.0f / 32768.0f)) * ((float)tot * (1.0f / 65536.0f));
        v += __shfl_xor(v, 1, 64);  v += __shfl_xor(v, 2, 64);
        v += __shfl_xor(v, 4, 64);  v += __shfl_xor(v, 8, 64);
        v += __shfl_xor(v, 16, 64); v += __shfl_xor(v, 32, 64);
        if (lane == 0) out_loss[0] = v * 0.64f;   // * E(64) * 0.01
    }
}

extern "C" void kernel_launch(void* const* d_in, const int* in_sizes, int n_in,
                              void* d_out, int out_size, void* d_ws, size_t ws_size,
                              hipStream_t stream) {
    const float* hs = (const float*)d_in[0];
    const float* Wg = (const float*)d_in[1];
    float* out = (float*)d_out;
    char*  ws  = (char*)d_ws;

    // ws layout (bytes):
    //   [0,      262144)  Wt   float[1024*64]
    //   [262144, 262400)  psum float[64]
    //   [262400, 786688)  rec  float4[32768]
    //   [786688, 917760)  hist int[512*64]
    float*  Wt   = (float*)ws;
    float*  psum = (float*)(ws + 262144);
    float4* rec  = (float4*)(ws + 262400);
    int*    hist = (int*)(ws + 786688);

    float* out_idx  = out;                 // 65536
    float* out_np   = out + 65536;         // 65536
    float* gp       = out + 131072;        // 2097152
    float* out_loss = out + 2228224;       // 1
    float* out_cm   = out + 2228225;       // 65536

    prep_kernel<<<256, 256, 0, stream>>>(Wg, Wt, psum);
    gate_kernel<<<512, 256, 0, stream>>>(hs, Wt, out_idx, gp, psum, rec, hist);
    scan_kernel<<<129, 64, 0, stream>>>(hist, rec, psum, out_np, out_cm, out_loss);
}

// Round 4
// 438.301 us; speedup vs baseline: 3.2427x; 3.2427x over previous
//
#include <hip/hip_runtime.h>

// Problem: B=4, S=8192, D=1024, E=64, K=2; tokens=32768; capacity=640
// Outputs (flat f32, concat): idx[65536] | norm_probs[65536] | gate_probs[2097152]
//                             | loss[1] | capacity_mask[65536]
#define CAPACITY 640

typedef __attribute__((ext_vector_type(16))) float f32x16;

// ------- prep: repack W[64][1024] -> Wt2[(c*16+wv)*128 + dl*4 + el], zero psum
// slice (c,wv): chunk c (32 d), wave wv owns experts 4wv..4wv+3; within slice
// index = dl*4 + el  (dl = d - 32c in 0..31, el = expert - 4wv in 0..3)
__global__ void prep_kernel(const float* __restrict__ Wg,
                            float* __restrict__ Wt2,
                            float* __restrict__ psum) {
    const int g = (int)(blockIdx.x * 256 + threadIdx.x);     // 65536 threads
    const int el = g & 3;
    const int dl = (g >> 2) & 31;
    const int wv = (g >> 7) & 15;
    const int c  = g >> 11;
    Wt2[g] = Wg[(size_t)((wv << 2) + el) * 1024 + (c << 5) + dl];
    if (g < 64) psum[g] = 0.0f;
}

// ---------------- main gate kernel --------------------------------------
// grid 512 (64 tokens each), block 1024 = 16 waves; wave w owns experts [4w,4w+4)
// Bit-exact numpy SSE3 einsum emulation:
//   - 4 j-partial accumulators (j = d&3), no FMA (contract off)
//   - per 32-d chunk, 4-d group execution order {3,2,1,0,7,6,5,4}
//   - final combine (p0+p1)+(p2+p3)
__global__ __launch_bounds__(1024, 8) void gate_kernel(
    const float* __restrict__ hs, const float* __restrict__ Wt2,
    float* __restrict__ out_idx, float* __restrict__ gp,
    float* __restrict__ psum, float4* __restrict__ rec, int* __restrict__ hist)
{
#pragma clang fp contract(off)
    __shared__ float  lds_h[2][2048];   // [buf][64 rows * 32 floats], source-swizzled
    __shared__ float  red_m[16][64];
    __shared__ float  red_s[16][64];
    __shared__ float4 red_t[16][64];    // v1, idx1(asfloat), v2, idx2(asfloat)

    const int tid  = (int)threadIdx.x;
    const int lane = tid & 63;
    const int w    = tid >> 6;
    const int wslice = __builtin_amdgcn_readfirstlane(w);   // uniform -> s_load path
    const int tokBase = (int)blockIdx.x << 6;

    float4 a0 = {0,0,0,0}, a1 = {0,0,0,0}, a2 = {0,0,0,0}, a3 = {0,0,0,0};

    const int r8  = lane >> 3;            // row-within-8 for staging
    const int kgl = (lane & 7) ^ r8;      // pre-swizzled 16B-group (bank-conflict fix)

    auto stage = [&](int buf, int c) {
        if (w < 8) {
            const float* g = hs + (size_t)(tokBase + (w << 3) + r8) * 1024
                                + (c << 5) + (kgl << 2);
            __builtin_amdgcn_global_load_lds(
                (__attribute__((address_space(1))) void*)g,
                (__attribute__((address_space(3))) void*)&lds_h[buf][w << 8],
                16, 0, 0);
        }
    };

#define ACC_J(HC, WV, O, C) \
    { float t0 = (HC) * (WV)[(O)+0]; a0.C = a0.C + t0; \
      float t1 = (HC) * (WV)[(O)+1]; a1.C = a1.C + t1; \
      float t2 = (HC) * (WV)[(O)+2]; a2.C = a2.C + t2; \
      float t3 = (HC) * (WV)[(O)+3]; a3.C = a3.C + t3; }

#define DO_G(G) { \
    const f32x16 wv16 = *(const f32x16*)(wp + ((G) << 4)); \
    const float4 h4 = *(const float4*)&lds_h[buf][(lane << 5) + (((G) ^ (lane & 7)) << 2)]; \
    ACC_J(h4.x, wv16,  0, x) \
    ACC_J(h4.y, wv16,  4, y) \
    ACC_J(h4.z, wv16,  8, z) \
    ACC_J(h4.w, wv16, 12, w) }

    stage(0, 0);
    __syncthreads();
    int buf = 0;
    for (int c = 0; c < 32; ++c) {
        if (c < 31) stage(buf ^ 1, c + 1);            // prefetch next chunk
        const float* wp = Wt2 + (((c << 4) + wslice) << 7);   // uniform, contiguous 512B
        DO_G(3) DO_G(2) DO_G(1) DO_G(0)               // numpy chain order
        DO_G(7) DO_G(6) DO_G(5) DO_G(4)
        __syncthreads();   // drains vmcnt for the prefetch, flips epoch
        buf ^= 1;
    }
#undef DO_G
#undef ACC_J

    // final horizontal combine, numpy npyv_sum_f32 (SSE3): (p0+p1)+(p2+p3)
    float logit[4];
    {
        const float4 av[4] = {a0, a1, a2, a3};
#pragma unroll
        for (int e = 0; e < 4; ++e) {
            const float s01 = av[e].x + av[e].y;
            const float s23 = av[e].z + av[e].w;
            logit[e] = s01 + s23;
        }
    }

    // ---- epilogue: cross-wave softmax assembly (lane = token) ----
    const int woff = wslice << 2;
    float m = fmaxf(fmaxf(logit[0], logit[1]), fmaxf(logit[2], logit[3]));
    red_m[w][lane] = m;
    __syncthreads();
    float gm = red_m[0][lane];
#pragma unroll
    for (int ww = 1; ww < 16; ++ww) gm = fmaxf(gm, red_m[ww][lane]);

    float p[4];
    float s = 0.0f;
#pragma unroll
    for (int e = 0; e < 4; ++e) { p[e] = __expf(logit[e] - gm); s += p[e]; }
    red_s[w][lane] = s;

    // slice top-2 on logits (strict > keeps lowest index on ties)
    float v1 = -3.4e38f, v2 = -3.4e38f; int i1 = 0, i2 = 0;
#pragma unroll
    for (int e = 0; e < 4; ++e) {
        const float v = logit[e];
        if (v > v1)      { v2 = v1; i2 = i1; v1 = v; i1 = woff + e; }
        else if (v > v2) { v2 = v;  i2 = woff + e; }
    }
    red_t[w][lane] = make_float4(v1, __int_as_float(i1), v2, __int_as_float(i2));
    __syncthreads();
    float stot = red_s[0][lane];
#pragma unroll
    for (int ww = 1; ww < 16; ++ww) stot += red_s[ww][lane];
    const float inv  = 1.0f / stot;
    const int token  = tokBase + lane;

    // gate_probs slice store + per-expert prob sums
    float pn[4];
#pragma unroll
    for (int e = 0; e < 4; ++e) pn[e] = p[e] * inv;
    *(float4*)&gp[(size_t)token * 64 + woff] = make_float4(pn[0], pn[1], pn[2], pn[3]);

    float mysum = 0.0f;
#pragma unroll
    for (int e = 0; e < 4; ++e) {
        float v = pn[e];
        v += __shfl_xor(v, 1, 64);  v += __shfl_xor(v, 2, 64);
        v += __shfl_xor(v, 4, 64);  v += __shfl_xor(v, 8, 64);
        v += __shfl_xor(v, 16, 64); v += __shfl_xor(v, 32, 64);
        if (lane == e) mysum = v;
    }
    if (lane < 4) atomicAdd(&psum[woff + lane], mysum);

    if (w == 0) {
        // merge 16 slice top-2s (ascending index blocks -> ties keep earlier)
        float4 aa = red_t[0][lane];
        float g1 = aa.x; int gi1 = __float_as_int(aa.y);
        float g2 = aa.z; int gi2 = __float_as_int(aa.w);
#pragma unroll
        for (int ww = 1; ww < 16; ++ww) {
            const float4 bb = red_t[ww][lane];
            const float b1 = bb.x; const int bi1 = __float_as_int(bb.y);
            const float b2 = bb.z; const int bi2 = __float_as_int(bb.w);
            if (b1 > g1)      { g2 = g1; gi2 = gi1; g1 = b1; gi1 = bi1; }
            else if (b1 > g2) { g2 = b1; gi2 = bi1; }
            if (b2 > g2)      { g2 = b2; gi2 = bi2; }
        }
        const float p1 = __expf(g1 - gm) * inv;
        const float p2 = __expf(g2 - gm) * inv;
        *(float2*)&out_idx[2 * token] = make_float2((float)gi1, (float)gi2);
        rec[token] = make_float4(__int_as_float(gi1 | (gi2 << 8)), p1, p2, 0.0f);

        // per-block expert histogram via 6-bit ballot match (no LDS atomics)
        int cnt = 0;
#pragma unroll
        for (int which = 0; which < 2; ++which) {
            const int ei = which ? gi2 : gi1;
            const unsigned long long m0 = __ballot(ei & 1);
            const unsigned long long m1 = __ballot((ei >> 1) & 1);
            const unsigned long long m2 = __ballot((ei >> 2) & 1);
            const unsigned long long m3 = __ballot((ei >> 3) & 1);
            const unsigned long long m4 = __ballot((ei >> 4) & 1);
            const unsigned long long m5 = __ballot((ei >> 5) & 1);
            unsigned long long mine = (lane & 1)        ? m0 : ~m0;
            mine &= ((lane >> 1) & 1) ? m1 : ~m1;
            mine &= ((lane >> 2) & 1) ? m2 : ~m2;
            mine &= ((lane >> 3) & 1) ? m3 : ~m3;
            mine &= ((lane >> 4) & 1) ? m4 : ~m4;
            mine &= ((lane >> 5) & 1) ? m5 : ~m5;
            cnt += __popcll(mine);   // # lanes whose index == my lane id
        }
        hist[((int)blockIdx.x << 6) + lane] = cnt;
    }
}

// ---------------- scan: capacity ranks + outputs + loss ------------------
// blocks 0..127: 512 slots each; block 128: loss. 64 threads = 1 wave.
__global__ __launch_bounds__(64) void scan_kernel(
    const int* __restrict__ hist, const float4* __restrict__ rec,
    const float* __restrict__ psum, float* __restrict__ out_np,
    float* __restrict__ out_cm, float* __restrict__ out_loss)
{
    const int lane = (int)threadIdx.x;
    const int b = (int)blockIdx.x;
    if (b < 128) {
        int cnt = 0;                       // lane l = running count for expert l
        const int abase = b << 2;          // 4 gate-blocks per scan-block
        for (int a = 0; a < abase; ++a) cnt += hist[(a << 6) + lane];
#pragma unroll
        for (int it = 0; it < 8; ++it) {
            const int slot  = (b << 9) + (it << 6) + lane;
            const int token = slot >> 1;
            const int kk    = slot & 1;
            const float4 r  = rec[token];
            const int packed = __float_as_int(r.x);
            const int e  = kk ? ((packed >> 8) & 63) : (packed & 63);
            const float pv = kk ? r.z : r.y;
            const unsigned long long m0 = __ballot(e & 1);
            const unsigned long long m1 = __ballot((e >> 1) & 1);
            const unsigned long long m2 = __ballot((e >> 2) & 1);
            const unsigned long long m3 = __ballot((e >> 3) & 1);
            const unsigned long long m4 = __ballot((e >> 4) & 1);
            const unsigned long long m5 = __ballot((e >> 5) & 1);
            unsigned long long peers = (e & 1)        ? m0 : ~m0;
            peers &= ((e >> 1) & 1) ? m1 : ~m1;
            peers &= ((e >> 2) & 1) ? m2 : ~m2;
            peers &= ((e >> 3) & 1) ? m3 : ~m3;
            peers &= ((e >> 4) & 1) ? m4 : ~m4;
            peers &= ((e >> 5) & 1) ? m5 : ~m5;
            unsigned long long mine = (lane & 1)        ? m0 : ~m0;
            mine &= ((lane >> 1) & 1) ? m1 : ~m1;
            mine &= ((lane >> 2) & 1) ? m2 : ~m2;
            mine &= ((lane >> 3) & 1) ? m3 : ~m3;
            mine &= ((lane >> 4) & 1) ? m4 : ~m4;
            mine &= ((lane >> 5) & 1) ? m5 : ~m5;
            const int base = __shfl(cnt, e, 64);
            const int rank = base + __popcll(peers & ((1ull << lane) - 1ull));
            const bool keep = rank < CAPACITY;
            cnt += __popcll(mine);
            const float masked = keep ? pv : 0.0f;
            const float other  = __shfl_xor(masked, 1, 64);
            float denom = masked + other;
            denom = denom > 1e-8f ? denom : 1e-8f;
            out_np[slot] = masked / denom;
            out_cm[slot] = keep ? 1.0f : 0.0f;
        }
    } else {
        int tot = 0;
        for (int a = 0; a < 512; ++a) tot += hist[(a << 6) + lane];
        float v = (psum[lane] * (1.0f / 32768.0f)) * ((float)tot * (1.0f / 65536.0f));
        v += __shfl_xor(v, 1, 64);  v += __shfl_xor(v, 2, 64);
        v += __shfl_xor(v, 4, 64);  v += __shfl_xor(v, 8, 64);
        v += __shfl_xor(v, 16, 64); v += __shfl_xor(v, 32, 64);
        if (lane == 0) out_loss[0] = v * 0.64f;   // * E(64) * 0.01
    }
}

extern "C" void kernel_launch(void* const* d_in, const int* in_sizes, int n_in,
                              void* d_out, int out_size, void* d_ws, size_t ws_size,
                              hipStream_t stream) {
    const float* hs = (const float*)d_in[0];
    const float* Wg = (const float*)d_in[1];
    float* out = (float*)d_out;
    char*  ws  = (char*)d_ws;

    // ws layout (bytes):
    //   [0,      262144)  Wt2  float[32*16*128]
    //   [262144, 262400)  psum float[64]
    //   [262400, 786688)  rec  float4[32768]
    //   [786688, 917760)  hist int[512*64]
    float*  Wt2  = (float*)ws;
    float*  psum = (float*)(ws + 262144);
    float4* rec  = (float4*)(ws + 262400);
    int*    hist = (int*)(ws + 786688);

    float* out_idx  = out;                 // 65536
    float* out_np   = out + 65536;         // 65536
    float* gp       = out + 131072;        // 2097152
    float* out_loss = out + 2228224;       // 1
    float* out_cm   = out + 2228225;       // 65536

    prep_kernel<<<256, 256, 0, stream>>>(Wg, Wt2, psum);
    gate_kernel<<<512, 1024, 0, stream>>>(hs, Wt2, out_idx, gp, psum, rec, hist);
    scan_kernel<<<129, 64, 0, stream>>>(hist, rec, psum, out_np, out_cm, out_loss);
}